// Round 14
// baseline (95.549 us; speedup 1.0000x reference)
//
#include <hip/hip_runtime.h>
#include <cstdint>

typedef unsigned short u16;
using short8 = __attribute__((ext_vector_type(8))) short;
using f32x4  = __attribute__((ext_vector_type(4))) float;

#define T1 512
#define T2 832
#define NH 16
#define NPLOC 448

__device__ __forceinline__ u16 f2b(float f){
  union { float f; uint32_t u; } c; c.f = f;
  uint32_t u = c.u;
  u += 0x7fffu + ((u >> 16) & 1u);   // RNE bf16
  return (u16)(u >> 16);
}
__device__ __forceinline__ float b2f(u16 b){
  union { uint32_t u; float f; } c; c.u = (uint32_t)b << 16; return c.f;
}
__device__ __forceinline__ void async16(const void* g, void* l){
  __builtin_amdgcn_global_load_lds(
      (const __attribute__((address_space(1))) unsigned int*)g,
      (__attribute__((address_space(3))) unsigned int*)l, 16, 0, 0);
}
// add f32 bias (8 contiguous) to a bf16x8 fragment, once per block (prologue only)
__device__ __forceinline__ short8 addbias(short8 q, const float* bp){
  short8 r;
  #pragma unroll
  for (int j = 0; j < 8; ++j) r[j] = (short)f2b(b2f((u16)q[j]) + bp[j]);
  return r;
}

#define SB0 __builtin_amdgcn_sched_barrier(0)

// ---------------- fused f32 -> bf16 convert (activations + weights) ----------------
struct CvtSeg { const float* src; u16* dst; int nblk; };
struct CvtArgs { CvtSeg s[9]; };

__global__ __launch_bounds__(256) void cvt_all(CvtArgs a){
  int rel = blockIdx.x, seg = 0;
  while (rel >= a.s[seg].nblk){ rel -= a.s[seg].nblk; ++seg; }
  int i = rel * 256 + threadIdx.x;
  float4 v = ((const float4*)a.s[seg].src)[i];
  uint64_t p = (uint64_t)f2b(v.x) | ((uint64_t)f2b(v.y) << 16)
             | ((uint64_t)f2b(v.z) << 32) | ((uint64_t)f2b(v.w) << 48);
  *(uint64_t*)(a.s[seg].dst + (size_t)i * 4) = p;
}

// ---------------- gemm4: 128x128 tile, 512 threads (8 waves), dual-buffer vmcnt(2) ----------------
// Same R8-proven schedule; wave-tile 32x64 (acc[2][4]); 18 resident waves/CU (was 9).
struct G4Args {
  const u16 *q, *k, *v, *p;
  const u16 *Wq, *Wk, *Wv, *Wp;
  const float *bq, *bk, *bv;
  u16 *qatt, *katt, *vatt, *patt;
  float *cache;
};

__global__ __launch_bounds__(512, 4) void gemm4(G4Args ga){
  __shared__ __align__(16) u16 As0[4096];
  __shared__ __align__(16) u16 As1[4096];
  __shared__ __align__(16) u16 Bs0[4096];
  __shared__ __align__(16) u16 Bs1[4096];

  int bid0 = blockIdx.x;
  int bid = (bid0 & 7) * 72 + (bid0 >> 3);   // XCD swizzle (576 = 8*72)
  int tid = threadIdx.x;
  int mode, mb; const u16 *A, *W;
  if (bid < 128)      { mode = 0; mb = bid >> 3;         A = ga.q; W = ga.Wq; }
  else if (bid < 336) { mode = 1; mb = (bid - 128) >> 3; A = ga.k; W = ga.Wk; }
  else if (bid < 544) { mode = 2; mb = (bid - 336) >> 3; A = ga.v; W = ga.Wv; }
  else                { mode = 3; mb = (bid - 544) >> 3; A = ga.p; W = ga.Wp; }
  int m0 = mb * 128, n0 = (bid & 7) * 128;

  int lane = tid & 63, w = tid >> 6;         // w in 0..7
  int wr = w >> 1, wc = w & 1;               // wave-tile: rows [wr*32,+32), cols [wc*64,+64)
  const int lr = lane & 15, g = lane >> 4;
  const int sslot = (g ^ ((lr >> 1) & 3)) * 8;

  int r = tid >> 2;                          // 0..127
  int ssl = ((tid & 3) ^ ((tid >> 3) & 3)) * 8;
  const u16* Asrc = A + (size_t)(m0 + r) * 1024 + ssl;
  const u16* Bsrc = W + (size_t)(n0 + r) * 1024 + ssl;

  f32x4 acc[2][4] = {};

  auto stage = [&](int k0, u16* as, u16* bs){   // 2 DMAs/thread = one K-tile
    async16(Asrc + k0, as + tid*8);
    async16(Bsrc + k0, bs + tid*8);
  };

  auto step = [&](u16* as, u16* bs, int kstage, bool do_stage, bool last){
    if (last) asm volatile("s_waitcnt vmcnt(0)" ::: "memory");
    else      asm volatile("s_waitcnt vmcnt(2)" ::: "memory");
    SB0; __builtin_amdgcn_s_barrier(); SB0;
    short8 a[2], b[4];
    #pragma unroll
    for (int m = 0; m < 2; ++m) a[m] = *(const short8*)&as[(wr*32 + m*16 + lr)*32 + sslot];
    #pragma unroll
    for (int n = 0; n < 4; ++n) b[n] = *(const short8*)&bs[(wc*64 + n*16 + lr)*32 + sslot];
    asm volatile("s_waitcnt lgkmcnt(0)" ::: "memory");
    SB0; __builtin_amdgcn_s_barrier(); SB0;
    if (do_stage) stage(kstage, as, bs);
    SB0;
    __builtin_amdgcn_s_setprio(1);
    #pragma unroll
    for (int m = 0; m < 2; ++m)
      #pragma unroll
      for (int n = 0; n < 4; ++n)
        acc[m][n] = __builtin_amdgcn_mfma_f32_16x16x32_bf16(a[m], b[n], acc[m][n], 0, 0, 0);
    __builtin_amdgcn_s_setprio(0);
  };

  stage(0,  As0, Bs0);
  stage(32, As1, Bs1);
  SB0;
  for (int it = 0; it < 16; ++it){
    step(As0, Bs0, it*64 + 64, it < 15, false);
    step(As1, Bs1, it*64 + 96, it < 15, it == 15);
  }

  // ---- epilogue ----
  #pragma unroll
  for (int m = 0; m < 2; ++m){
    #pragma unroll
    for (int n = 0; n < 4; ++n){
      #pragma unroll
      for (int j = 0; j < 4; ++j){
        int row = m0 + wr*32 + m*16 + g*4 + j;
        int col = n0 + wc*64 + n*16 + lr;
        float vv = acc[m][n][j];
        if (mode == 0){
          vv += ga.bq[col];                          // pos biases added in attn prologue
          int h = col >> 6, d = col & 63, b_ = row >> 9, t = row & 511;
          size_t o = ((size_t)((b_*NH + h)*T1 + t))*64 + d;
          ga.qatt[o] = f2b(vv);
        } else if (mode == 1 || mode == 2){
          vv += (mode == 1 ? ga.bk : ga.bv)[col];
          int h = col >> 6, d = col & 63;
          int b_ = row / T2, t2 = row - b_*T2;
          size_t base = (size_t)(b_*NH + h)*T2 + t2;
          ga.cache[base*128 + (mode == 2 ? 64 : 0) + d] = vv;
          (mode == 1 ? ga.katt : ga.vatt)[base*64 + d] = f2b(vv);
        } else {
          if (row < NPLOC){
            int h = col >> 6, d = col & 63;
            ga.patt[((size_t)h*NPLOC + row)*64 + d] = f2b(vv);
          }
        }
      }
    }
  }
}

// ---------------- gemm_out: 64x64 tiles, 512 blocks (2/CU), R8 schedule ----------------
__global__ __launch_bounds__(256, 4) void gemm_out(const u16* __restrict__ A, const u16* __restrict__ W,
                                                   const float* __restrict__ bias, float* __restrict__ out){
  __shared__ __align__(16) u16 As0[2048];
  __shared__ __align__(16) u16 As1[2048];
  __shared__ __align__(16) u16 Bs0[2048];
  __shared__ __align__(16) u16 Bs1[2048];

  int bid0 = blockIdx.x;
  int bid = (bid0 & 7) * 64 + (bid0 >> 3);   // XCD swizzle (512 = 8*64)
  int m0 = (bid >> 4) * 64, n0 = (bid & 15) * 64;
  int tid = threadIdx.x;

  int lane = tid & 63, w = tid >> 6;
  int wr = w >> 1, wc = w & 1;
  const int lr = lane & 15, g = lane >> 4;
  const int sslot = (g ^ ((lr >> 1) & 3)) * 8;

  int r = tid >> 2;
  int ssl = ((tid & 3) ^ ((tid >> 3) & 3)) * 8;
  const u16* Asrc = A + (size_t)(m0 + r) * 1024 + ssl;
  const u16* Bsrc = W + (size_t)(n0 + r) * 1024 + ssl;

  f32x4 acc[2][2] = {};

  auto stage = [&](int k0, u16* as, u16* bs){
    async16(Asrc + k0, as + tid*8);
    async16(Bsrc + k0, bs + tid*8);
  };

  auto step = [&](u16* as, u16* bs, int kstage, bool do_stage, bool last){
    if (last) asm volatile("s_waitcnt vmcnt(0)" ::: "memory");
    else      asm volatile("s_waitcnt vmcnt(2)" ::: "memory");
    SB0; __builtin_amdgcn_s_barrier(); SB0;
    short8 a[2], b[2];
    #pragma unroll
    for (int m = 0; m < 2; ++m) a[m] = *(const short8*)&as[(wr*32 + m*16 + lr)*32 + sslot];
    #pragma unroll
    for (int n = 0; n < 2; ++n) b[n] = *(const short8*)&bs[(wc*32 + n*16 + lr)*32 + sslot];
    asm volatile("s_waitcnt lgkmcnt(0)" ::: "memory");
    SB0; __builtin_amdgcn_s_barrier(); SB0;
    if (do_stage) stage(kstage, as, bs);
    SB0;
    __builtin_amdgcn_s_setprio(1);
    #pragma unroll
    for (int m = 0; m < 2; ++m)
      #pragma unroll
      for (int n = 0; n < 2; ++n)
        acc[m][n] = __builtin_amdgcn_mfma_f32_16x16x32_bf16(a[m], b[n], acc[m][n], 0, 0, 0);
    __builtin_amdgcn_s_setprio(0);
  };

  stage(0,  As0, Bs0);
  stage(32, As1, Bs1);
  SB0;
  for (int it = 0; it < 16; ++it){
    step(As0, Bs0, it*64 + 64, it < 15, false);
    step(As1, Bs1, it*64 + 96, it < 15, it == 15);
  }

  #pragma unroll
  for (int m = 0; m < 2; ++m)
    #pragma unroll
    for (int n = 0; n < 2; ++n)
      #pragma unroll
      for (int j = 0; j < 4; ++j){
        int row = m0 + wr*32 + m*16 + g*4 + j;
        int col = n0 + wc*32 + n*16 + lr;
        out[(size_t)row*1024 + col] = acc[m][n][j] + bias[col];
      }
}

// ---------------- attention v3 (R8-proven) + in-register pos-bias add ----------------
#define PHASE_HEAD(N) \
  asm volatile("s_waitcnt vmcnt(" #N ")" ::: "memory"); \
  SB0; __builtin_amdgcn_s_barrier(); SB0;

#define PHASE_TAIL \
  SB0; __builtin_amdgcn_s_barrier(); SB0;

#define VT_TAIL \
  asm volatile("s_waitcnt lgkmcnt(0)" ::: "memory"); \
  SB0; __builtin_amdgcn_s_barrier(); SB0;

__global__ __launch_bounds__(256, 2) void attn_v3(
    const u16* __restrict__ qatt,
    const u16* __restrict__ katt, const u16* __restrict__ vatt,
    const u16* __restrict__ patt,
    const float* __restrict__ pbu, const float* __restrict__ pbv,
    u16* __restrict__ xout)
{
  __shared__ __align__(16) u16 SB[64*384];   // 49152 B (bd scores -> P)
  __shared__ __align__(16) u16 S0[8192];     // 16384 B staging ping
  __shared__ __align__(16) u16 S1[8192];     // 16384 B staging pong

  int tid = threadIdx.x, lane = tid & 63, w = tid >> 6;
  int bid0 = blockIdx.x;
  int bid = (bid0 & 7) * 64 + (bid0 >> 3);   // XCD swizzle
  int c = bid & 7, h = (bid >> 3) & 15, b = bid >> 7;
  int bh = b*NH + h;
  const int lr = lane & 15, g = lane >> 4, lk = g * 8;

  auto sb_off = [&](int r, int cc) -> uint32_t {
    return ((uint32_t)(r*384 + cc)*2) ^ ((uint32_t)(r & 15) << 4);
  };
  auto stg_swz = [&](uint32_t o) -> uint32_t { return o ^ (((o >> 7) & 7u) << 4); };
  auto vt_off = [&](int d, int kk) -> uint32_t {
    return ((uint32_t)(d*128 + kk)*2) ^ ((uint32_t)(((d & 7) ^ ((d >> 3) & 7))) << 4);
  };

  // Q once (bias-only bf16), pos biases added in-register
  int qrow = 16*w + lr;
  const u16* qb = qatt + ((size_t)bh*T1 + c*64 + qrow)*64;
  short8 q0 = *(const short8*)(qb + lk);
  short8 q1 = *(const short8*)(qb + 32 + lk);
  const float* bu = pbu + h*64;
  const float* bv = pbv + h*64;
  short8 qu0 = addbias(q0, bu + lk);
  short8 qu1 = addbias(q1, bu + 32 + lk);
  short8 qv0 = addbias(q0, bv + lk);
  short8 qv1 = addbias(q1, bv + 32 + lk);
  SB0;

  const char* psrc = (const char*)(patt + (size_t)h*NPLOC*64);
  const char* ksrc = (const char*)(katt + ((size_t)bh*T2 + c*64)*64);
  const u16*  vsrc = vatt + ((size_t)bh*T2 + c*64)*64;

  auto issue4 = [&](const char* src, u16* dst){
    #pragma unroll
    for (int i = 0; i < 4; ++i){
      uint32_t o = (uint32_t)(i*256 + tid)*16;
      async16(src + stg_swz(o), (char*)dst + o);
    }
  };

  uint4 vstg0, vstg1, vstg2, vstg3;
  auto vload = [&](int vc){
    const u16* vb = vsrc + vc*8192;
    vstg0 = *(const uint4*)(vb + (0*256 + tid)*8);
    vstg1 = *(const uint4*)(vb + (1*256 + tid)*8);
    vstg2 = *(const uint4*)(vb + (2*256 + tid)*8);
    vstg3 = *(const uint4*)(vb + (3*256 + tid)*8);
  };
  auto vtwrite = [&](u16* sbuf){
    #pragma unroll
    for (int i = 0; i < 4; ++i){
      uint4 vv4 = (i == 0) ? vstg0 : (i == 1) ? vstg1 : (i == 2) ? vstg2 : vstg3;
      int e = (i*256 + tid)*8;
      int kk = e >> 6, d0 = e & 63;
      u16 uu[8] = { (u16)(vv4.x & 0xffff), (u16)(vv4.x >> 16), (u16)(vv4.y & 0xffff), (u16)(vv4.y >> 16),
                    (u16)(vv4.z & 0xffff), (u16)(vv4.z >> 16), (u16)(vv4.w & 0xffff), (u16)(vv4.w >> 16) };
      #pragma unroll
      for (int j = 0; j < 8; ++j)
        *(u16*)((char*)sbuf + vt_off(d0 + j, kk)) = uu[j];
    }
  };

  #define BD_CHUNK(PC, SBUF) \
    _Pragma("unroll") \
    for (int nt = 0; nt < 8; ++nt){ \
      uint32_t bo = (uint32_t)((nt*16 + lr)*64)*2; \
      short8 b0 = *(const short8*)((const char*)SBUF + stg_swz(bo + lk*2)); \
      short8 b1 = *(const short8*)((const char*)SBUF + stg_swz(bo + (32 + lk)*2)); \
      f32x4 acc = {0.f,0.f,0.f,0.f}; \
      __builtin_amdgcn_s_setprio(1); \
      acc = __builtin_amdgcn_mfma_f32_16x16x32_bf16(qv0, b0, acc, 0, 0, 0); \
      acc = __builtin_amdgcn_mfma_f32_16x16x32_bf16(qv1, b1, acc, 0, 0, 0); \
      __builtin_amdgcn_s_setprio(0); \
      int nl = (PC)*128 + nt*16 + lr; \
      _Pragma("unroll") \
      for (int j = 0; j < 4; ++j){ \
        int r = 16*w + g*4 + j; \
        int jj = nl + r - 63; \
        if (jj >= 0 && jj < 384) *(u16*)((char*)SB + sb_off(r, jj)) = f2b(acc[j]); \
      } \
    }

  #define AC_CHUNK(KC, SBUF) \
    _Pragma("unroll") \
    for (int nt = 0; nt < 8; ++nt){ \
      uint32_t bo = (uint32_t)((nt*16 + lr)*64)*2; \
      short8 b0 = *(const short8*)((const char*)SBUF + stg_swz(bo + lk*2)); \
      short8 b1 = *(const short8*)((const char*)SBUF + stg_swz(bo + (32 + lk)*2)); \
      __builtin_amdgcn_s_setprio(1); \
      accs[(KC)*8 + nt] = __builtin_amdgcn_mfma_f32_16x16x32_bf16(qu0, b0, accs[(KC)*8 + nt], 0, 0, 0); \
      accs[(KC)*8 + nt] = __builtin_amdgcn_mfma_f32_16x16x32_bf16(qu1, b1, accs[(KC)*8 + nt], 0, 0, 0); \
      __builtin_amdgcn_s_setprio(0); \
    }

  #define PV_CHUNK(VC, SBUF) \
    _Pragma("unroll") \
    for (int kt = 0; kt < 4; ++kt){ \
      short8 a = *(const short8*)((const char*)SB + sb_off(16*w + lr, (VC)*128 + kt*32 + lk)); \
      __builtin_amdgcn_s_setprio(1); \
      _Pragma("unroll") \
      for (int n = 0; n < 4; ++n){ \
        short8 bb = *(const short8*)((const char*)SBUF + vt_off(n*16 + lr, kt*32 + lk)); \
        acco[n] = __builtin_amdgcn_mfma_f32_16x16x32_bf16(a, bb, acco[n], 0, 0, 0); \
      } \
      __builtin_amdgcn_s_setprio(0); \
    }

  f32x4 accs[24];
  #pragma unroll
  for (int t = 0; t < 24; ++t) accs[t] = (f32x4){0.f,0.f,0.f,0.f};
  f32x4 acco[4] = {};

  issue4(psrc,          S0);
  issue4(psrc + 16384,  S1);

  PHASE_HEAD(4) BD_CHUNK(0, S0) PHASE_TAIL issue4(psrc + 32768, S0);
  PHASE_HEAD(4) BD_CHUNK(1, S1) PHASE_TAIL issue4(psrc + 49152, S1);
  PHASE_HEAD(4) BD_CHUNK(2, S0) PHASE_TAIL issue4(ksrc,         S0);
  PHASE_HEAD(4) BD_CHUNK(3, S1) PHASE_TAIL issue4(ksrc + 16384, S1);
  PHASE_HEAD(4) AC_CHUNK(0, S0) PHASE_TAIL issue4(ksrc + 32768, S0);
  PHASE_HEAD(4) AC_CHUNK(1, S1) PHASE_TAIL vload(0);
  PHASE_HEAD(4) AC_CHUNK(2, S0)

  // ---- softmax in registers ----
  #pragma unroll
  for (int t = 0; t < 24; ++t)
    #pragma unroll
    for (int j = 0; j < 4; ++j){
      int r = 16*w + g*4 + j, cc = t*16 + lr;
      accs[t][j] += b2f(*(const u16*)((const char*)SB + sb_off(r, cc)));
    }
  float mx[4] = {-1e30f,-1e30f,-1e30f,-1e30f};
  #pragma unroll
  for (int t = 0; t < 24; ++t)
    #pragma unroll
    for (int j = 0; j < 4; ++j) mx[j] = fmaxf(mx[j], accs[t][j]);
  #pragma unroll
  for (int j = 0; j < 4; ++j){
    mx[j] = fmaxf(mx[j], __shfl_xor(mx[j], 1));
    mx[j] = fmaxf(mx[j], __shfl_xor(mx[j], 2));
    mx[j] = fmaxf(mx[j], __shfl_xor(mx[j], 4));
    mx[j] = fmaxf(mx[j], __shfl_xor(mx[j], 8));
  }
  float sm[4] = {0.f,0.f,0.f,0.f};
  #pragma unroll
  for (int t = 0; t < 24; ++t)
    #pragma unroll
    for (int j = 0; j < 4; ++j){
      accs[t][j] = __expf((accs[t][j] - mx[j]) * 0.125f);
      sm[j] += accs[t][j];
    }
  #pragma unroll
  for (int j = 0; j < 4; ++j){
    sm[j] += __shfl_xor(sm[j], 1);
    sm[j] += __shfl_xor(sm[j], 2);
    sm[j] += __shfl_xor(sm[j], 4);
    sm[j] += __shfl_xor(sm[j], 8);
    sm[j] = 1.f / sm[j];
  }
  #pragma unroll
  for (int t = 0; t < 24; ++t)
    #pragma unroll
    for (int j = 0; j < 4; ++j){
      int r = 16*w + g*4 + j, cc = t*16 + lr;
      *(u16*)((char*)SB + sb_off(r, cc)) = f2b(accs[t][j] * sm[j]);
    }

  asm volatile("s_waitcnt vmcnt(0)" ::: "memory");
  SB0;
  vtwrite(S1);
  vload(1);
  VT_TAIL

  PV_CHUNK(0, S1)
  asm volatile("s_waitcnt vmcnt(0)" ::: "memory");
  SB0;
  vtwrite(S0);
  vload(2);
  VT_TAIL

  PV_CHUNK(1, S0)
  asm volatile("s_waitcnt vmcnt(0)" ::: "memory");
  SB0;
  vtwrite(S1);
  VT_TAIL

  PV_CHUNK(2, S1)

  #pragma unroll
  for (int n = 0; n < 4; ++n)
    #pragma unroll
    for (int j = 0; j < 4; ++j){
      int r = 16*w + g*4 + j;
      int t = c*64 + r, d = n*16 + lr;
      xout[((size_t)b*T1 + t)*1024 + h*64 + d] = f2b(acco[n][j]);
    }
}

// ---------------- launch ----------------
extern "C" void kernel_launch(void* const* d_in, const int* in_sizes, int n_in,
                              void* d_out, int out_size, void* d_ws, size_t ws_size,
                              hipStream_t stream)
{
  const float* query = (const float*)d_in[0];
  const float* key   = (const float*)d_in[1];
  const float* value = (const float*)d_in[2];
  const float* pos   = (const float*)d_in[3];
  const float* Wq  = (const float*)d_in[4];
  const float* bq  = (const float*)d_in[5];
  const float* Wk  = (const float*)d_in[6];
  const float* bk  = (const float*)d_in[7];
  const float* Wv  = (const float*)d_in[8];
  const float* bv  = (const float*)d_in[9];
  const float* Wp  = (const float*)d_in[10];
  const float* Wo  = (const float*)d_in[11];
  const float* bo  = (const float*)d_in[12];
  const float* pbu = (const float*)d_in[13];
  const float* pbv = (const float*)d_in[14];

  float* out   = (float*)d_out;
  float* cache = out + 2097152;

  u16* ws     = (u16*)d_ws;
  u16* q_bf   = ws;
  u16* key_bf = ws + 2097152;
  u16* val_bf = ws + 5505024;
  u16* pos_bf = ws + 8912896;
  u16* Wq_bf  = ws + 9437184;
  u16* Wk_bf  = ws + 10485760;
  u16* Wv_bf  = ws + 11534336;
  u16* Wp_bf  = ws + 12582912;
  u16* Wo_bf  = ws + 13631488;
  u16* qatt   = ws + 14680064;
  u16* katt   = ws + 18874368;
  u16* vatt   = ws + 22282240;
  u16* patt   = ws + 25690112;
  u16* x_bf   = ws + 26148864;

  CvtArgs ca;
  ca.s[0] = { query,            q_bf,   2048 };
  ca.s[1] = { key,              key_bf, 3328 };
  ca.s[2] = { value,            val_bf, 3328 };
  ca.s[3] = { Wq,               Wq_bf,  1024 };
  ca.s[4] = { Wk,               Wk_bf,  1024 };
  ca.s[5] = { Wv,               Wv_bf,  1024 };
  ca.s[6] = { Wp,               Wp_bf,  1024 };
  ca.s[7] = { Wo,               Wo_bf,  1024 };
  ca.s[8] = { pos + 448*1024,   pos_bf, 448 };
  cvt_all<<<14272, 256, 0, stream>>>(ca);

  G4Args ga;
  ga.q = q_bf; ga.k = key_bf; ga.v = val_bf; ga.p = pos_bf;
  ga.Wq = Wq_bf; ga.Wk = Wk_bf; ga.Wv = Wv_bf; ga.Wp = Wp_bf;
  ga.bq = bq; ga.bk = bk; ga.bv = bv;
  ga.qatt = qatt; ga.katt = katt; ga.vatt = vatt; ga.patt = patt;
  ga.cache = cache;
  gemm4<<<576, 512, 0, stream>>>(ga);

  attn_v3<<<512, 256, 0, stream>>>(qatt, katt, vatt, patt, pbu, pbv, x_bf);

  gemm_out<<<512, 256, 0, stream>>>(x_bf, Wo_bf, bo, out);
}

// Round 15
// 93.379 us; speedup vs baseline: 1.0232x; 1.0232x over previous
//
#include <hip/hip_runtime.h>
#include <cstdint>

typedef unsigned short u16;
using short8 = __attribute__((ext_vector_type(8))) short;
using f32x4  = __attribute__((ext_vector_type(4))) float;

#define T1 512
#define T2 832
#define NH 16
#define NPLOC 448

__device__ __forceinline__ u16 f2b(float f){
  union { float f; uint32_t u; } c; c.f = f;
  uint32_t u = c.u;
  u += 0x7fffu + ((u >> 16) & 1u);   // RNE bf16
  return (u16)(u >> 16);
}
__device__ __forceinline__ float b2f(u16 b){
  union { uint32_t u; float f; } c; c.u = (uint32_t)b << 16; return c.f;
}
__device__ __forceinline__ void async16(const void* g, void* l){
  __builtin_amdgcn_global_load_lds(
      (const __attribute__((address_space(1))) unsigned int*)g,
      (__attribute__((address_space(3))) unsigned int*)l, 16, 0, 0);
}
// add f32 bias (8 contiguous) to a bf16x8 fragment, once per block (prologue only)
__device__ __forceinline__ short8 addbias(short8 q, const float* bp){
  short8 r;
  #pragma unroll
  for (int j = 0; j < 8; ++j) r[j] = (short)f2b(b2f((u16)q[j]) + bp[j]);
  return r;
}

#define SB0 __builtin_amdgcn_sched_barrier(0)

// ---------------- fused f32 -> bf16 convert (activations + weights) ----------------
struct CvtSeg { const float* src; u16* dst; int nblk; };
struct CvtArgs { CvtSeg s[9]; };

__global__ __launch_bounds__(256) void cvt_all(CvtArgs a){
  int rel = blockIdx.x, seg = 0;
  while (rel >= a.s[seg].nblk){ rel -= a.s[seg].nblk; ++seg; }
  int i = rel * 256 + threadIdx.x;
  float4 v = ((const float4*)a.s[seg].src)[i];
  uint64_t p = (uint64_t)f2b(v.x) | ((uint64_t)f2b(v.y) << 16)
             | ((uint64_t)f2b(v.z) << 32) | ((uint64_t)f2b(v.w) << 48);
  *(uint64_t*)(a.s[seg].dst + (size_t)i * 4) = p;
}

// ---------------- R8/R12-proven dual-buffer counted-vmcnt GEMM core, 128x128 ----------------
// Lockstep barrier structure: setprio REMOVED (T5/m190: ~0 to negative on this structure).
struct G4Args {
  const u16 *q, *k, *v, *p;
  const u16 *Wq, *Wk, *Wv, *Wp;
  const float *bq, *bk, *bv;
  u16 *qatt, *katt, *vatt, *patt;
  float *cache;
};

__global__ __launch_bounds__(256, 4) void gemm4(G4Args ga){
  __shared__ __align__(16) u16 As0[4096];
  __shared__ __align__(16) u16 As1[4096];
  __shared__ __align__(16) u16 Bs0[4096];
  __shared__ __align__(16) u16 Bs1[4096];

  int bid0 = blockIdx.x;
  int bid = (bid0 & 7) * 72 + (bid0 >> 3);   // XCD swizzle (576 = 8*72)
  int tid = threadIdx.x;
  int mode, mb; const u16 *A, *W;
  if (bid < 128)      { mode = 0; mb = bid >> 3;         A = ga.q; W = ga.Wq; }
  else if (bid < 336) { mode = 1; mb = (bid - 128) >> 3; A = ga.k; W = ga.Wk; }
  else if (bid < 544) { mode = 2; mb = (bid - 336) >> 3; A = ga.v; W = ga.Wv; }
  else                { mode = 3; mb = (bid - 544) >> 3; A = ga.p; W = ga.Wp; }
  int m0 = mb * 128, n0 = (bid & 7) * 128;

  int lane = tid & 63, w = tid >> 6;
  int wr = w >> 1, wc = w & 1;
  const int lr = lane & 15, g = lane >> 4;
  const int sslot = (g ^ ((lr >> 1) & 3)) * 8;

  int r = tid >> 2;
  int ssl = ((tid & 3) ^ ((tid >> 3) & 3)) * 8;
  const u16* Asrc = A + (size_t)(m0 + r) * 1024 + ssl;
  const u16* Bsrc = W + (size_t)(n0 + r) * 1024 + ssl;

  f32x4 acc[4][4] = {};

  auto stage = [&](int k0, u16* as, u16* bs){
    async16(Asrc + k0,         as + tid*8);
    async16(Asrc + 65536 + k0, as + 2048 + tid*8);
    async16(Bsrc + k0,         bs + tid*8);
    async16(Bsrc + 65536 + k0, bs + 2048 + tid*8);
  };

  auto step = [&](u16* as, u16* bs, int kstage, bool do_stage, bool last){
    if (last) asm volatile("s_waitcnt vmcnt(0)" ::: "memory");
    else      asm volatile("s_waitcnt vmcnt(4)" ::: "memory");
    SB0; __builtin_amdgcn_s_barrier(); SB0;
    short8 a[4], b[4];
    #pragma unroll
    for (int m = 0; m < 4; ++m) a[m] = *(const short8*)&as[(wr*64 + m*16 + lr)*32 + sslot];
    #pragma unroll
    for (int n = 0; n < 4; ++n) b[n] = *(const short8*)&bs[(wc*64 + n*16 + lr)*32 + sslot];
    asm volatile("s_waitcnt lgkmcnt(0)" ::: "memory");
    SB0; __builtin_amdgcn_s_barrier(); SB0;
    if (do_stage) stage(kstage, as, bs);
    SB0;
    #pragma unroll
    for (int m = 0; m < 4; ++m)
      #pragma unroll
      for (int n = 0; n < 4; ++n)
        acc[m][n] = __builtin_amdgcn_mfma_f32_16x16x32_bf16(a[m], b[n], acc[m][n], 0, 0, 0);
  };

  stage(0,  As0, Bs0);
  stage(32, As1, Bs1);
  SB0;
  for (int it = 0; it < 16; ++it){
    step(As0, Bs0, it*64 + 64, it < 15, false);
    step(As1, Bs1, it*64 + 96, it < 15, it == 15);
  }

  // ---- epilogue ----
  #pragma unroll
  for (int m = 0; m < 4; ++m){
    #pragma unroll
    for (int n = 0; n < 4; ++n){
      #pragma unroll
      for (int j = 0; j < 4; ++j){
        int row = m0 + wr*64 + m*16 + g*4 + j;
        int col = n0 + wc*64 + n*16 + lr;
        float vv = acc[m][n][j];
        if (mode == 0){
          vv += ga.bq[col];                          // pos biases added in attn prologue
          int h = col >> 6, d = col & 63, b_ = row >> 9, t = row & 511;
          size_t o = ((size_t)((b_*NH + h)*T1 + t))*64 + d;
          ga.qatt[o] = f2b(vv);
        } else if (mode == 1 || mode == 2){
          vv += (mode == 1 ? ga.bk : ga.bv)[col];
          int h = col >> 6, d = col & 63;
          int b_ = row / T2, t2 = row - b_*T2;
          size_t base = (size_t)(b_*NH + h)*T2 + t2;
          ga.cache[base*128 + (mode == 2 ? 64 : 0) + d] = vv;
          (mode == 1 ? ga.katt : ga.vatt)[base*64 + d] = f2b(vv);
        } else {
          if (row < NPLOC){
            int h = col >> 6, d = col & 63;
            ga.patt[((size_t)h*NPLOC + row)*64 + d] = f2b(vv);
          }
        }
      }
    }
  }
}

// ---------------- gemm_out: 64x64 tiles, 512 blocks (2/CU), R8 schedule ----------------
__global__ __launch_bounds__(256, 4) void gemm_out(const u16* __restrict__ A, const u16* __restrict__ W,
                                                   const float* __restrict__ bias, float* __restrict__ out){
  __shared__ __align__(16) u16 As0[2048];
  __shared__ __align__(16) u16 As1[2048];
  __shared__ __align__(16) u16 Bs0[2048];
  __shared__ __align__(16) u16 Bs1[2048];

  int bid0 = blockIdx.x;
  int bid = (bid0 & 7) * 64 + (bid0 >> 3);   // XCD swizzle (512 = 8*64)
  int m0 = (bid >> 4) * 64, n0 = (bid & 15) * 64;
  int tid = threadIdx.x;

  int lane = tid & 63, w = tid >> 6;
  int wr = w >> 1, wc = w & 1;
  const int lr = lane & 15, g = lane >> 4;
  const int sslot = (g ^ ((lr >> 1) & 3)) * 8;

  int r = tid >> 2;
  int ssl = ((tid & 3) ^ ((tid >> 3) & 3)) * 8;
  const u16* Asrc = A + (size_t)(m0 + r) * 1024 + ssl;
  const u16* Bsrc = W + (size_t)(n0 + r) * 1024 + ssl;

  f32x4 acc[2][2] = {};

  auto stage = [&](int k0, u16* as, u16* bs){
    async16(Asrc + k0, as + tid*8);
    async16(Bsrc + k0, bs + tid*8);
  };

  auto step = [&](u16* as, u16* bs, int kstage, bool do_stage, bool last){
    if (last) asm volatile("s_waitcnt vmcnt(0)" ::: "memory");
    else      asm volatile("s_waitcnt vmcnt(2)" ::: "memory");
    SB0; __builtin_amdgcn_s_barrier(); SB0;
    short8 a[2], b[2];
    #pragma unroll
    for (int m = 0; m < 2; ++m) a[m] = *(const short8*)&as[(wr*32 + m*16 + lr)*32 + sslot];
    #pragma unroll
    for (int n = 0; n < 2; ++n) b[n] = *(const short8*)&bs[(wc*32 + n*16 + lr)*32 + sslot];
    asm volatile("s_waitcnt lgkmcnt(0)" ::: "memory");
    SB0; __builtin_amdgcn_s_barrier(); SB0;
    if (do_stage) stage(kstage, as, bs);
    SB0;
    #pragma unroll
    for (int m = 0; m < 2; ++m)
      #pragma unroll
      for (int n = 0; n < 2; ++n)
        acc[m][n] = __builtin_amdgcn_mfma_f32_16x16x32_bf16(a[m], b[n], acc[m][n], 0, 0, 0);
  };

  stage(0,  As0, Bs0);
  stage(32, As1, Bs1);
  SB0;
  for (int it = 0; it < 16; ++it){
    step(As0, Bs0, it*64 + 64, it < 15, false);
    step(As1, Bs1, it*64 + 96, it < 15, it == 15);
  }

  #pragma unroll
  for (int m = 0; m < 2; ++m)
    #pragma unroll
    for (int n = 0; n < 2; ++n)
      #pragma unroll
      for (int j = 0; j < 4; ++j){
        int row = m0 + wr*32 + m*16 + g*4 + j;
        int col = n0 + wc*32 + n*16 + lr;
        out[(size_t)row*1024 + col] = acc[m][n][j] + bias[col];
      }
}

// ---------------- attention v3 (R8-proven) + in-register pos-bias add ----------------
#define PHASE_HEAD(N) \
  asm volatile("s_waitcnt vmcnt(" #N ")" ::: "memory"); \
  SB0; __builtin_amdgcn_s_barrier(); SB0;

#define PHASE_TAIL \
  SB0; __builtin_amdgcn_s_barrier(); SB0;

#define VT_TAIL \
  asm volatile("s_waitcnt lgkmcnt(0)" ::: "memory"); \
  SB0; __builtin_amdgcn_s_barrier(); SB0;

__global__ __launch_bounds__(256, 2) void attn_v3(
    const u16* __restrict__ qatt,
    const u16* __restrict__ katt, const u16* __restrict__ vatt,
    const u16* __restrict__ patt,
    const float* __restrict__ pbu, const float* __restrict__ pbv,
    u16* __restrict__ xout)
{
  __shared__ __align__(16) u16 SB[64*384];   // 49152 B (bd scores -> P)
  __shared__ __align__(16) u16 S0[8192];     // 16384 B staging ping
  __shared__ __align__(16) u16 S1[8192];     // 16384 B staging pong

  int tid = threadIdx.x, lane = tid & 63, w = tid >> 6;
  int bid0 = blockIdx.x;
  int bid = (bid0 & 7) * 64 + (bid0 >> 3);   // XCD swizzle
  int c = bid & 7, h = (bid >> 3) & 15, b = bid >> 7;
  int bh = b*NH + h;
  const int lr = lane & 15, g = lane >> 4, lk = g * 8;

  auto sb_off = [&](int r, int cc) -> uint32_t {
    return ((uint32_t)(r*384 + cc)*2) ^ ((uint32_t)(r & 15) << 4);
  };
  auto stg_swz = [&](uint32_t o) -> uint32_t { return o ^ (((o >> 7) & 7u) << 4); };
  auto vt_off = [&](int d, int kk) -> uint32_t {
    return ((uint32_t)(d*128 + kk)*2) ^ ((uint32_t)(((d & 7) ^ ((d >> 3) & 7))) << 4);
  };

  // Q once (bias-only bf16), pos biases added in-register
  int qrow = 16*w + lr;
  const u16* qb = qatt + ((size_t)bh*T1 + c*64 + qrow)*64;
  short8 q0 = *(const short8*)(qb + lk);
  short8 q1 = *(const short8*)(qb + 32 + lk);
  const float* bu = pbu + h*64;
  const float* bv = pbv + h*64;
  short8 qu0 = addbias(q0, bu + lk);
  short8 qu1 = addbias(q1, bu + 32 + lk);
  short8 qv0 = addbias(q0, bv + lk);
  short8 qv1 = addbias(q1, bv + 32 + lk);
  SB0;

  const char* psrc = (const char*)(patt + (size_t)h*NPLOC*64);
  const char* ksrc = (const char*)(katt + ((size_t)bh*T2 + c*64)*64);
  const u16*  vsrc = vatt + ((size_t)bh*T2 + c*64)*64;

  auto issue4 = [&](const char* src, u16* dst){
    #pragma unroll
    for (int i = 0; i < 4; ++i){
      uint32_t o = (uint32_t)(i*256 + tid)*16;
      async16(src + stg_swz(o), (char*)dst + o);
    }
  };

  uint4 vstg0, vstg1, vstg2, vstg3;
  auto vload = [&](int vc){
    const u16* vb = vsrc + vc*8192;
    vstg0 = *(const uint4*)(vb + (0*256 + tid)*8);
    vstg1 = *(const uint4*)(vb + (1*256 + tid)*8);
    vstg2 = *(const uint4*)(vb + (2*256 + tid)*8);
    vstg3 = *(const uint4*)(vb + (3*256 + tid)*8);
  };
  auto vtwrite = [&](u16* sbuf){
    #pragma unroll
    for (int i = 0; i < 4; ++i){
      uint4 vv4 = (i == 0) ? vstg0 : (i == 1) ? vstg1 : (i == 2) ? vstg2 : vstg3;
      int e = (i*256 + tid)*8;
      int kk = e >> 6, d0 = e & 63;
      u16 uu[8] = { (u16)(vv4.x & 0xffff), (u16)(vv4.x >> 16), (u16)(vv4.y & 0xffff), (u16)(vv4.y >> 16),
                    (u16)(vv4.z & 0xffff), (u16)(vv4.z >> 16), (u16)(vv4.w & 0xffff), (u16)(vv4.w >> 16) };
      #pragma unroll
      for (int j = 0; j < 8; ++j)
        *(u16*)((char*)sbuf + vt_off(d0 + j, kk)) = uu[j];
    }
  };

  #define BD_CHUNK(PC, SBUF) \
    _Pragma("unroll") \
    for (int nt = 0; nt < 8; ++nt){ \
      uint32_t bo = (uint32_t)((nt*16 + lr)*64)*2; \
      short8 b0 = *(const short8*)((const char*)SBUF + stg_swz(bo + lk*2)); \
      short8 b1 = *(const short8*)((const char*)SBUF + stg_swz(bo + (32 + lk)*2)); \
      f32x4 acc = {0.f,0.f,0.f,0.f}; \
      __builtin_amdgcn_s_setprio(1); \
      acc = __builtin_amdgcn_mfma_f32_16x16x32_bf16(qv0, b0, acc, 0, 0, 0); \
      acc = __builtin_amdgcn_mfma_f32_16x16x32_bf16(qv1, b1, acc, 0, 0, 0); \
      __builtin_amdgcn_s_setprio(0); \
      int nl = (PC)*128 + nt*16 + lr; \
      _Pragma("unroll") \
      for (int j = 0; j < 4; ++j){ \
        int r = 16*w + g*4 + j; \
        int jj = nl + r - 63; \
        if (jj >= 0 && jj < 384) *(u16*)((char*)SB + sb_off(r, jj)) = f2b(acc[j]); \
      } \
    }

  #define AC_CHUNK(KC, SBUF) \
    _Pragma("unroll") \
    for (int nt = 0; nt < 8; ++nt){ \
      uint32_t bo = (uint32_t)((nt*16 + lr)*64)*2; \
      short8 b0 = *(const short8*)((const char*)SBUF + stg_swz(bo + lk*2)); \
      short8 b1 = *(const short8*)((const char*)SBUF + stg_swz(bo + (32 + lk)*2)); \
      __builtin_amdgcn_s_setprio(1); \
      accs[(KC)*8 + nt] = __builtin_amdgcn_mfma_f32_16x16x32_bf16(qu0, b0, accs[(KC)*8 + nt], 0, 0, 0); \
      accs[(KC)*8 + nt] = __builtin_amdgcn_mfma_f32_16x16x32_bf16(qu1, b1, accs[(KC)*8 + nt], 0, 0, 0); \
      __builtin_amdgcn_s_setprio(0); \
    }

  #define PV_CHUNK(VC, SBUF) \
    _Pragma("unroll") \
    for (int kt = 0; kt < 4; ++kt){ \
      short8 a = *(const short8*)((const char*)SB + sb_off(16*w + lr, (VC)*128 + kt*32 + lk)); \
      __builtin_amdgcn_s_setprio(1); \
      _Pragma("unroll") \
      for (int n = 0; n < 4; ++n){ \
        short8 bb = *(const short8*)((const char*)SBUF + vt_off(n*16 + lr, kt*32 + lk)); \
        acco[n] = __builtin_amdgcn_mfma_f32_16x16x32_bf16(a, bb, acco[n], 0, 0, 0); \
      } \
      __builtin_amdgcn_s_setprio(0); \
    }

  f32x4 accs[24];
  #pragma unroll
  for (int t = 0; t < 24; ++t) accs[t] = (f32x4){0.f,0.f,0.f,0.f};
  f32x4 acco[4] = {};

  issue4(psrc,          S0);
  issue4(psrc + 16384,  S1);

  PHASE_HEAD(4) BD_CHUNK(0, S0) PHASE_TAIL issue4(psrc + 32768, S0);
  PHASE_HEAD(4) BD_CHUNK(1, S1) PHASE_TAIL issue4(psrc + 49152, S1);
  PHASE_HEAD(4) BD_CHUNK(2, S0) PHASE_TAIL issue4(ksrc,         S0);
  PHASE_HEAD(4) BD_CHUNK(3, S1) PHASE_TAIL issue4(ksrc + 16384, S1);
  PHASE_HEAD(4) AC_CHUNK(0, S0) PHASE_TAIL issue4(ksrc + 32768, S0);
  PHASE_HEAD(4) AC_CHUNK(1, S1) PHASE_TAIL vload(0);
  PHASE_HEAD(4) AC_CHUNK(2, S0)

  // ---- softmax in registers ----
  #pragma unroll
  for (int t = 0; t < 24; ++t)
    #pragma unroll
    for (int j = 0; j < 4; ++j){
      int r = 16*w + g*4 + j, cc = t*16 + lr;
      accs[t][j] += b2f(*(const u16*)((const char*)SB + sb_off(r, cc)));
    }
  float mx[4] = {-1e30f,-1e30f,-1e30f,-1e30f};
  #pragma unroll
  for (int t = 0; t < 24; ++t)
    #pragma unroll
    for (int j = 0; j < 4; ++j) mx[j] = fmaxf(mx[j], accs[t][j]);
  #pragma unroll
  for (int j = 0; j < 4; ++j){
    mx[j] = fmaxf(mx[j], __shfl_xor(mx[j], 1));
    mx[j] = fmaxf(mx[j], __shfl_xor(mx[j], 2));
    mx[j] = fmaxf(mx[j], __shfl_xor(mx[j], 4));
    mx[j] = fmaxf(mx[j], __shfl_xor(mx[j], 8));
  }
  float sm[4] = {0.f,0.f,0.f,0.f};
  #pragma unroll
  for (int t = 0; t < 24; ++t)
    #pragma unroll
    for (int j = 0; j < 4; ++j){
      accs[t][j] = __expf((accs[t][j] - mx[j]) * 0.125f);
      sm[j] += accs[t][j];
    }
  #pragma unroll
  for (int j = 0; j < 4; ++j){
    sm[j] += __shfl_xor(sm[j], 1);
    sm[j] += __shfl_xor(sm[j], 2);
    sm[j] += __shfl_xor(sm[j], 4);
    sm[j] += __shfl_xor(sm[j], 8);
    sm[j] = 1.f / sm[j];
  }
  #pragma unroll
  for (int t = 0; t < 24; ++t)
    #pragma unroll
    for (int j = 0; j < 4; ++j){
      int r = 16*w + g*4 + j, cc = t*16 + lr;
      *(u16*)((char*)SB + sb_off(r, cc)) = f2b(accs[t][j] * sm[j]);
    }

  asm volatile("s_waitcnt vmcnt(0)" ::: "memory");
  SB0;
  vtwrite(S1);
  vload(1);
  VT_TAIL

  PV_CHUNK(0, S1)
  asm volatile("s_waitcnt vmcnt(0)" ::: "memory");
  SB0;
  vtwrite(S0);
  vload(2);
  VT_TAIL

  PV_CHUNK(1, S0)
  asm volatile("s_waitcnt vmcnt(0)" ::: "memory");
  SB0;
  vtwrite(S1);
  VT_TAIL

  PV_CHUNK(2, S1)

  #pragma unroll
  for (int n = 0; n < 4; ++n)
    #pragma unroll
    for (int j = 0; j < 4; ++j){
      int r = 16*w + g*4 + j;
      int t = c*64 + r, d = n*16 + lr;
      xout[((size_t)b*T1 + t)*1024 + h*64 + d] = f2b(acco[n][j]);
    }
}

// ---------------- launch ----------------
extern "C" void kernel_launch(void* const* d_in, const int* in_sizes, int n_in,
                              void* d_out, int out_size, void* d_ws, size_t ws_size,
                              hipStream_t stream)
{
  const float* query = (const float*)d_in[0];
  const float* key   = (const float*)d_in[1];
  const float* value = (const float*)d_in[2];
  const float* pos   = (const float*)d_in[3];
  const float* Wq  = (const float*)d_in[4];
  const float* bq  = (const float*)d_in[5];
  const float* Wk  = (const float*)d_in[6];
  const float* bk  = (const float*)d_in[7];
  const float* Wv  = (const float*)d_in[8];
  const float* bv  = (const float*)d_in[9];
  const float* Wp  = (const float*)d_in[10];
  const float* Wo  = (const float*)d_in[11];
  const float* bo  = (const float*)d_in[12];
  const float* pbu = (const float*)d_in[13];
  const float* pbv = (const float*)d_in[14];

  float* out   = (float*)d_out;
  float* cache = out + 2097152;

  u16* ws     = (u16*)d_ws;
  u16* q_bf   = ws;
  u16* key_bf = ws + 2097152;
  u16* val_bf = ws + 5505024;
  u16* pos_bf = ws + 8912896;
  u16* Wq_bf  = ws + 9437184;
  u16* Wk_bf  = ws + 10485760;
  u16* Wv_bf  = ws + 11534336;
  u16* Wp_bf  = ws + 12582912;
  u16* Wo_bf  = ws + 13631488;
  u16* qatt   = ws + 14680064;
  u16* katt   = ws + 18874368;
  u16* vatt   = ws + 22282240;
  u16* patt   = ws + 25690112;
  u16* x_bf   = ws + 26148864;

  CvtArgs ca;
  ca.s[0] = { query,            q_bf,   2048 };
  ca.s[1] = { key,              key_bf, 3328 };
  ca.s[2] = { value,            val_bf, 3328 };
  ca.s[3] = { Wq,               Wq_bf,  1024 };
  ca.s[4] = { Wk,               Wk_bf,  1024 };
  ca.s[5] = { Wv,               Wv_bf,  1024 };
  ca.s[6] = { Wp,               Wp_bf,  1024 };
  ca.s[7] = { Wo,               Wo_bf,  1024 };
  ca.s[8] = { pos + 448*1024,   pos_bf, 448 };
  cvt_all<<<14272, 256, 0, stream>>>(ca);

  G4Args ga;
  ga.q = q_bf; ga.k = key_bf; ga.v = val_bf; ga.p = pos_bf;
  ga.Wq = Wq_bf; ga.Wk = Wk_bf; ga.Wv = Wv_bf; ga.Wp = Wp_bf;
  ga.bq = bq; ga.bk = bk; ga.bv = bv;
  ga.qatt = qatt; ga.katt = katt; ga.vatt = vatt; ga.patt = patt;
  ga.cache = cache;
  gemm4<<<576, 256, 0, stream>>>(ga);

  attn_v3<<<512, 256, 0, stream>>>(qatt, katt, vatt, patt, pbu, pbv, x_bf);

  gemm_out<<<512, 256, 0, stream>>>(x_bf, Wo_bf, bo, out);
}

// Round 16
// 90.167 us; speedup vs baseline: 1.0597x; 1.0356x over previous
//
#include <hip/hip_runtime.h>
#include <cstdint>

typedef unsigned short u16;
using short8 = __attribute__((ext_vector_type(8))) short;
using f32x4  = __attribute__((ext_vector_type(4))) float;

#define T1 512
#define T2 832
#define NH 16
#define NPLOC 448

__device__ __forceinline__ u16 f2b(float f){
  union { float f; uint32_t u; } c; c.f = f;
  uint32_t u = c.u;
  u += 0x7fffu + ((u >> 16) & 1u);   // RNE bf16
  return (u16)(u >> 16);
}
__device__ __forceinline__ float b2f(u16 b){
  union { uint32_t u; float f; } c; c.u = (uint32_t)b << 16; return c.f;
}
__device__ __forceinline__ void async16(const void* g, void* l){
  __builtin_amdgcn_global_load_lds(
      (const __attribute__((address_space(1))) unsigned int*)g,
      (__attribute__((address_space(3))) unsigned int*)l, 16, 0, 0);
}
// add f32 bias (8 contiguous) to a bf16x8 fragment, once per block (prologue only)
__device__ __forceinline__ short8 addbias(short8 q, const float* bp){
  short8 r;
  #pragma unroll
  for (int j = 0; j < 8; ++j) r[j] = (short)f2b(b2f((u16)q[j]) + bp[j]);
  return r;
}

#define SB0 __builtin_amdgcn_sched_barrier(0)

// ---------------- fused f32 -> bf16 convert (activations + weights) ----------------
struct CvtSeg { const float* src; u16* dst; int nblk; };
struct CvtArgs { CvtSeg s[9]; };

__global__ __launch_bounds__(256) void cvt_all(CvtArgs a){
  int rel = blockIdx.x, seg = 0;
  while (rel >= a.s[seg].nblk){ rel -= a.s[seg].nblk; ++seg; }
  int i = rel * 256 + threadIdx.x;
  float4 v = ((const float4*)a.s[seg].src)[i];
  uint64_t p = (uint64_t)f2b(v.x) | ((uint64_t)f2b(v.y) << 16)
             | ((uint64_t)f2b(v.z) << 32) | ((uint64_t)f2b(v.w) << 48);
  *(uint64_t*)(a.s[seg].dst + (size_t)i * 4) = p;
}

// ---------------- R8/R12-proven dual-buffer counted-vmcnt GEMM core, 128x128 ----------------
// setprio RESTORED (R15 A/B: removal cost ~3 us total — counted-vmcnt loop has
// stage-vs-MFMA wave role diversity, so setprio pays here unlike pure lockstep).
struct G4Args {
  const u16 *q, *k, *v, *p;
  const u16 *Wq, *Wk, *Wv, *Wp;
  const float *bq, *bk, *bv;
  u16 *qatt, *katt, *vatt, *patt;
  float *cache;
};

__global__ __launch_bounds__(256, 4) void gemm4(G4Args ga){
  __shared__ __align__(16) u16 As0[4096];
  __shared__ __align__(16) u16 As1[4096];
  __shared__ __align__(16) u16 Bs0[4096];
  __shared__ __align__(16) u16 Bs1[4096];

  int bid0 = blockIdx.x;
  int bid = (bid0 & 7) * 72 + (bid0 >> 3);   // XCD swizzle (576 = 8*72)
  int tid = threadIdx.x;
  int mode, mb; const u16 *A, *W;
  if (bid < 128)      { mode = 0; mb = bid >> 3;         A = ga.q; W = ga.Wq; }
  else if (bid < 336) { mode = 1; mb = (bid - 128) >> 3; A = ga.k; W = ga.Wk; }
  else if (bid < 544) { mode = 2; mb = (bid - 336) >> 3; A = ga.v; W = ga.Wv; }
  else                { mode = 3; mb = (bid - 544) >> 3; A = ga.p; W = ga.Wp; }
  int m0 = mb * 128, n0 = (bid & 7) * 128;

  int lane = tid & 63, w = tid >> 6;
  int wr = w >> 1, wc = w & 1;
  const int lr = lane & 15, g = lane >> 4;
  const int sslot = (g ^ ((lr >> 1) & 3)) * 8;

  int r = tid >> 2;
  int ssl = ((tid & 3) ^ ((tid >> 3) & 3)) * 8;
  const u16* Asrc = A + (size_t)(m0 + r) * 1024 + ssl;
  const u16* Bsrc = W + (size_t)(n0 + r) * 1024 + ssl;

  f32x4 acc[4][4] = {};

  auto stage = [&](int k0, u16* as, u16* bs){
    async16(Asrc + k0,         as + tid*8);
    async16(Asrc + 65536 + k0, as + 2048 + tid*8);
    async16(Bsrc + k0,         bs + tid*8);
    async16(Bsrc + 65536 + k0, bs + 2048 + tid*8);
  };

  auto step = [&](u16* as, u16* bs, int kstage, bool do_stage, bool last){
    if (last) asm volatile("s_waitcnt vmcnt(0)" ::: "memory");
    else      asm volatile("s_waitcnt vmcnt(4)" ::: "memory");
    SB0; __builtin_amdgcn_s_barrier(); SB0;
    short8 a[4], b[4];
    #pragma unroll
    for (int m = 0; m < 4; ++m) a[m] = *(const short8*)&as[(wr*64 + m*16 + lr)*32 + sslot];
    #pragma unroll
    for (int n = 0; n < 4; ++n) b[n] = *(const short8*)&bs[(wc*64 + n*16 + lr)*32 + sslot];
    asm volatile("s_waitcnt lgkmcnt(0)" ::: "memory");
    SB0; __builtin_amdgcn_s_barrier(); SB0;
    if (do_stage) stage(kstage, as, bs);
    SB0;
    __builtin_amdgcn_s_setprio(1);
    #pragma unroll
    for (int m = 0; m < 4; ++m)
      #pragma unroll
      for (int n = 0; n < 4; ++n)
        acc[m][n] = __builtin_amdgcn_mfma_f32_16x16x32_bf16(a[m], b[n], acc[m][n], 0, 0, 0);
    __builtin_amdgcn_s_setprio(0);
  };

  stage(0,  As0, Bs0);
  stage(32, As1, Bs1);
  SB0;
  for (int it = 0; it < 16; ++it){
    step(As0, Bs0, it*64 + 64, it < 15, false);
    step(As1, Bs1, it*64 + 96, it < 15, it == 15);
  }

  // ---- epilogue ----
  #pragma unroll
  for (int m = 0; m < 4; ++m){
    #pragma unroll
    for (int n = 0; n < 4; ++n){
      #pragma unroll
      for (int j = 0; j < 4; ++j){
        int row = m0 + wr*64 + m*16 + g*4 + j;
        int col = n0 + wc*64 + n*16 + lr;
        float vv = acc[m][n][j];
        if (mode == 0){
          vv += ga.bq[col];                          // pos biases added in attn prologue
          int h = col >> 6, d = col & 63, b_ = row >> 9, t = row & 511;
          size_t o = ((size_t)((b_*NH + h)*T1 + t))*64 + d;
          ga.qatt[o] = f2b(vv);
        } else if (mode == 1 || mode == 2){
          vv += (mode == 1 ? ga.bk : ga.bv)[col];
          int h = col >> 6, d = col & 63;
          int b_ = row / T2, t2 = row - b_*T2;
          size_t base = (size_t)(b_*NH + h)*T2 + t2;
          ga.cache[base*128 + (mode == 2 ? 64 : 0) + d] = vv;
          (mode == 1 ? ga.katt : ga.vatt)[base*64 + d] = f2b(vv);
        } else {
          if (row < NPLOC){
            int h = col >> 6, d = col & 63;
            ga.patt[((size_t)h*NPLOC + row)*64 + d] = f2b(vv);
          }
        }
      }
    }
  }
}

// ---------------- gemm_out: 64x64 tiles, 512 blocks (2/CU), R8 schedule ----------------
__global__ __launch_bounds__(256, 4) void gemm_out(const u16* __restrict__ A, const u16* __restrict__ W,
                                                   const float* __restrict__ bias, float* __restrict__ out){
  __shared__ __align__(16) u16 As0[2048];
  __shared__ __align__(16) u16 As1[2048];
  __shared__ __align__(16) u16 Bs0[2048];
  __shared__ __align__(16) u16 Bs1[2048];

  int bid0 = blockIdx.x;
  int bid = (bid0 & 7) * 64 + (bid0 >> 3);   // XCD swizzle (512 = 8*64)
  int m0 = (bid >> 4) * 64, n0 = (bid & 15) * 64;
  int tid = threadIdx.x;

  int lane = tid & 63, w = tid >> 6;
  int wr = w >> 1, wc = w & 1;
  const int lr = lane & 15, g = lane >> 4;
  const int sslot = (g ^ ((lr >> 1) & 3)) * 8;

  int r = tid >> 2;
  int ssl = ((tid & 3) ^ ((tid >> 3) & 3)) * 8;
  const u16* Asrc = A + (size_t)(m0 + r) * 1024 + ssl;
  const u16* Bsrc = W + (size_t)(n0 + r) * 1024 + ssl;

  f32x4 acc[2][2] = {};

  auto stage = [&](int k0, u16* as, u16* bs){
    async16(Asrc + k0, as + tid*8);
    async16(Bsrc + k0, bs + tid*8);
  };

  auto step = [&](u16* as, u16* bs, int kstage, bool do_stage, bool last){
    if (last) asm volatile("s_waitcnt vmcnt(0)" ::: "memory");
    else      asm volatile("s_waitcnt vmcnt(2)" ::: "memory");
    SB0; __builtin_amdgcn_s_barrier(); SB0;
    short8 a[2], b[2];
    #pragma unroll
    for (int m = 0; m < 2; ++m) a[m] = *(const short8*)&as[(wr*32 + m*16 + lr)*32 + sslot];
    #pragma unroll
    for (int n = 0; n < 2; ++n) b[n] = *(const short8*)&bs[(wc*32 + n*16 + lr)*32 + sslot];
    asm volatile("s_waitcnt lgkmcnt(0)" ::: "memory");
    SB0; __builtin_amdgcn_s_barrier(); SB0;
    if (do_stage) stage(kstage, as, bs);
    SB0;
    __builtin_amdgcn_s_setprio(1);
    #pragma unroll
    for (int m = 0; m < 2; ++m)
      #pragma unroll
      for (int n = 0; n < 2; ++n)
        acc[m][n] = __builtin_amdgcn_mfma_f32_16x16x32_bf16(a[m], b[n], acc[m][n], 0, 0, 0);
    __builtin_amdgcn_s_setprio(0);
  };

  stage(0,  As0, Bs0);
  stage(32, As1, Bs1);
  SB0;
  for (int it = 0; it < 16; ++it){
    step(As0, Bs0, it*64 + 64, it < 15, false);
    step(As1, Bs1, it*64 + 96, it < 15, it == 15);
  }

  #pragma unroll
  for (int m = 0; m < 2; ++m)
    #pragma unroll
    for (int n = 0; n < 2; ++n)
      #pragma unroll
      for (int j = 0; j < 4; ++j){
        int row = m0 + wr*32 + m*16 + g*4 + j;
        int col = n0 + wc*32 + n*16 + lr;
        out[(size_t)row*1024 + col] = acc[m][n][j] + bias[col];
      }
}

// ---------------- attention v3 (R8-proven) + in-register pos-bias add ----------------
#define PHASE_HEAD(N) \
  asm volatile("s_waitcnt vmcnt(" #N ")" ::: "memory"); \
  SB0; __builtin_amdgcn_s_barrier(); SB0;

#define PHASE_TAIL \
  SB0; __builtin_amdgcn_s_barrier(); SB0;

#define VT_TAIL \
  asm volatile("s_waitcnt lgkmcnt(0)" ::: "memory"); \
  SB0; __builtin_amdgcn_s_barrier(); SB0;

__global__ __launch_bounds__(256, 2) void attn_v3(
    const u16* __restrict__ qatt,
    const u16* __restrict__ katt, const u16* __restrict__ vatt,
    const u16* __restrict__ patt,
    const float* __restrict__ pbu, const float* __restrict__ pbv,
    u16* __restrict__ xout)
{
  __shared__ __align__(16) u16 SB[64*384];   // 49152 B (bd scores -> P)
  __shared__ __align__(16) u16 S0[8192];     // 16384 B staging ping
  __shared__ __align__(16) u16 S1[8192];     // 16384 B staging pong

  int tid = threadIdx.x, lane = tid & 63, w = tid >> 6;
  int bid0 = blockIdx.x;
  int bid = (bid0 & 7) * 64 + (bid0 >> 3);   // XCD swizzle
  int c = bid & 7, h = (bid >> 3) & 15, b = bid >> 7;
  int bh = b*NH + h;
  const int lr = lane & 15, g = lane >> 4, lk = g * 8;

  auto sb_off = [&](int r, int cc) -> uint32_t {
    return ((uint32_t)(r*384 + cc)*2) ^ ((uint32_t)(r & 15) << 4);
  };
  auto stg_swz = [&](uint32_t o) -> uint32_t { return o ^ (((o >> 7) & 7u) << 4); };
  auto vt_off = [&](int d, int kk) -> uint32_t {
    return ((uint32_t)(d*128 + kk)*2) ^ ((uint32_t)(((d & 7) ^ ((d >> 3) & 7))) << 4);
  };

  // Q once (bias-only bf16), pos biases added in-register
  int qrow = 16*w + lr;
  const u16* qb = qatt + ((size_t)bh*T1 + c*64 + qrow)*64;
  short8 q0 = *(const short8*)(qb + lk);
  short8 q1 = *(const short8*)(qb + 32 + lk);
  const float* bu = pbu + h*64;
  const float* bv = pbv + h*64;
  short8 qu0 = addbias(q0, bu + lk);
  short8 qu1 = addbias(q1, bu + 32 + lk);
  short8 qv0 = addbias(q0, bv + lk);
  short8 qv1 = addbias(q1, bv + 32 + lk);
  SB0;

  const char* psrc = (const char*)(patt + (size_t)h*NPLOC*64);
  const char* ksrc = (const char*)(katt + ((size_t)bh*T2 + c*64)*64);
  const u16*  vsrc = vatt + ((size_t)bh*T2 + c*64)*64;

  auto issue4 = [&](const char* src, u16* dst){
    #pragma unroll
    for (int i = 0; i < 4; ++i){
      uint32_t o = (uint32_t)(i*256 + tid)*16;
      async16(src + stg_swz(o), (char*)dst + o);
    }
  };

  uint4 vstg0, vstg1, vstg2, vstg3;
  auto vload = [&](int vc){
    const u16* vb = vsrc + vc*8192;
    vstg0 = *(const uint4*)(vb + (0*256 + tid)*8);
    vstg1 = *(const uint4*)(vb + (1*256 + tid)*8);
    vstg2 = *(const uint4*)(vb + (2*256 + tid)*8);
    vstg3 = *(const uint4*)(vb + (3*256 + tid)*8);
  };
  auto vtwrite = [&](u16* sbuf){
    #pragma unroll
    for (int i = 0; i < 4; ++i){
      uint4 vv4 = (i == 0) ? vstg0 : (i == 1) ? vstg1 : (i == 2) ? vstg2 : vstg3;
      int e = (i*256 + tid)*8;
      int kk = e >> 6, d0 = e & 63;
      u16 uu[8] = { (u16)(vv4.x & 0xffff), (u16)(vv4.x >> 16), (u16)(vv4.y & 0xffff), (u16)(vv4.y >> 16),
                    (u16)(vv4.z & 0xffff), (u16)(vv4.z >> 16), (u16)(vv4.w & 0xffff), (u16)(vv4.w >> 16) };
      #pragma unroll
      for (int j = 0; j < 8; ++j)
        *(u16*)((char*)sbuf + vt_off(d0 + j, kk)) = uu[j];
    }
  };

  #define BD_CHUNK(PC, SBUF) \
    _Pragma("unroll") \
    for (int nt = 0; nt < 8; ++nt){ \
      uint32_t bo = (uint32_t)((nt*16 + lr)*64)*2; \
      short8 b0 = *(const short8*)((const char*)SBUF + stg_swz(bo + lk*2)); \
      short8 b1 = *(const short8*)((const char*)SBUF + stg_swz(bo + (32 + lk)*2)); \
      f32x4 acc = {0.f,0.f,0.f,0.f}; \
      __builtin_amdgcn_s_setprio(1); \
      acc = __builtin_amdgcn_mfma_f32_16x16x32_bf16(qv0, b0, acc, 0, 0, 0); \
      acc = __builtin_amdgcn_mfma_f32_16x16x32_bf16(qv1, b1, acc, 0, 0, 0); \
      __builtin_amdgcn_s_setprio(0); \
      int nl = (PC)*128 + nt*16 + lr; \
      _Pragma("unroll") \
      for (int j = 0; j < 4; ++j){ \
        int r = 16*w + g*4 + j; \
        int jj = nl + r - 63; \
        if (jj >= 0 && jj < 384) *(u16*)((char*)SB + sb_off(r, jj)) = f2b(acc[j]); \
      } \
    }

  #define AC_CHUNK(KC, SBUF) \
    _Pragma("unroll") \
    for (int nt = 0; nt < 8; ++nt){ \
      uint32_t bo = (uint32_t)((nt*16 + lr)*64)*2; \
      short8 b0 = *(const short8*)((const char*)SBUF + stg_swz(bo + lk*2)); \
      short8 b1 = *(const short8*)((const char*)SBUF + stg_swz(bo + (32 + lk)*2)); \
      __builtin_amdgcn_s_setprio(1); \
      accs[(KC)*8 + nt] = __builtin_amdgcn_mfma_f32_16x16x32_bf16(qu0, b0, accs[(KC)*8 + nt], 0, 0, 0); \
      accs[(KC)*8 + nt] = __builtin_amdgcn_mfma_f32_16x16x32_bf16(qu1, b1, accs[(KC)*8 + nt], 0, 0, 0); \
      __builtin_amdgcn_s_setprio(0); \
    }

  #define PV_CHUNK(VC, SBUF) \
    _Pragma("unroll") \
    for (int kt = 0; kt < 4; ++kt){ \
      short8 a = *(const short8*)((const char*)SB + sb_off(16*w + lr, (VC)*128 + kt*32 + lk)); \
      __builtin_amdgcn_s_setprio(1); \
      _Pragma("unroll") \
      for (int n = 0; n < 4; ++n){ \
        short8 bb = *(const short8*)((const char*)SBUF + vt_off(n*16 + lr, kt*32 + lk)); \
        acco[n] = __builtin_amdgcn_mfma_f32_16x16x32_bf16(a, bb, acco[n], 0, 0, 0); \
      } \
      __builtin_amdgcn_s_setprio(0); \
    }

  f32x4 accs[24];
  #pragma unroll
  for (int t = 0; t < 24; ++t) accs[t] = (f32x4){0.f,0.f,0.f,0.f};
  f32x4 acco[4] = {};

  issue4(psrc,          S0);
  issue4(psrc + 16384,  S1);

  PHASE_HEAD(4) BD_CHUNK(0, S0) PHASE_TAIL issue4(psrc + 32768, S0);
  PHASE_HEAD(4) BD_CHUNK(1, S1) PHASE_TAIL issue4(psrc + 49152, S1);
  PHASE_HEAD(4) BD_CHUNK(2, S0) PHASE_TAIL issue4(ksrc,         S0);
  PHASE_HEAD(4) BD_CHUNK(3, S1) PHASE_TAIL issue4(ksrc + 16384, S1);
  PHASE_HEAD(4) AC_CHUNK(0, S0) PHASE_TAIL issue4(ksrc + 32768, S0);
  PHASE_HEAD(4) AC_CHUNK(1, S1) PHASE_TAIL vload(0);
  PHASE_HEAD(4) AC_CHUNK(2, S0)

  // ---- softmax in registers ----
  #pragma unroll
  for (int t = 0; t < 24; ++t)
    #pragma unroll
    for (int j = 0; j < 4; ++j){
      int r = 16*w + g*4 + j, cc = t*16 + lr;
      accs[t][j] += b2f(*(const u16*)((const char*)SB + sb_off(r, cc)));
    }
  float mx[4] = {-1e30f,-1e30f,-1e30f,-1e30f};
  #pragma unroll
  for (int t = 0; t < 24; ++t)
    #pragma unroll
    for (int j = 0; j < 4; ++j) mx[j] = fmaxf(mx[j], accs[t][j]);
  #pragma unroll
  for (int j = 0; j < 4; ++j){
    mx[j] = fmaxf(mx[j], __shfl_xor(mx[j], 1));
    mx[j] = fmaxf(mx[j], __shfl_xor(mx[j], 2));
    mx[j] = fmaxf(mx[j], __shfl_xor(mx[j], 4));
    mx[j] = fmaxf(mx[j], __shfl_xor(mx[j], 8));
  }
  float sm[4] = {0.f,0.f,0.f,0.f};
  #pragma unroll
  for (int t = 0; t < 24; ++t)
    #pragma unroll
    for (int j = 0; j < 4; ++j){
      accs[t][j] = __expf((accs[t][j] - mx[j]) * 0.125f);
      sm[j] += accs[t][j];
    }
  #pragma unroll
  for (int j = 0; j < 4; ++j){
    sm[j] += __shfl_xor(sm[j], 1);
    sm[j] += __shfl_xor(sm[j], 2);
    sm[j] += __shfl_xor(sm[j], 4);
    sm[j] += __shfl_xor(sm[j], 8);
    sm[j] = 1.f / sm[j];
  }
  #pragma unroll
  for (int t = 0; t < 24; ++t)
    #pragma unroll
    for (int j = 0; j < 4; ++j){
      int r = 16*w + g*4 + j, cc = t*16 + lr;
      *(u16*)((char*)SB + sb_off(r, cc)) = f2b(accs[t][j] * sm[j]);
    }

  asm volatile("s_waitcnt vmcnt(0)" ::: "memory");
  SB0;
  vtwrite(S1);
  vload(1);
  VT_TAIL

  PV_CHUNK(0, S1)
  asm volatile("s_waitcnt vmcnt(0)" ::: "memory");
  SB0;
  vtwrite(S0);
  vload(2);
  VT_TAIL

  PV_CHUNK(1, S0)
  asm volatile("s_waitcnt vmcnt(0)" ::: "memory");
  SB0;
  vtwrite(S1);
  VT_TAIL

  PV_CHUNK(2, S1)

  #pragma unroll
  for (int n = 0; n < 4; ++n)
    #pragma unroll
    for (int j = 0; j < 4; ++j){
      int r = 16*w + g*4 + j;
      int t = c*64 + r, d = n*16 + lr;
      xout[((size_t)b*T1 + t)*1024 + h*64 + d] = f2b(acco[n][j]);
    }
}

// ---------------- launch ----------------
extern "C" void kernel_launch(void* const* d_in, const int* in_sizes, int n_in,
                              void* d_out, int out_size, void* d_ws, size_t ws_size,
                              hipStream_t stream)
{
  const float* query = (const float*)d_in[0];
  const float* key   = (const float*)d_in[1];
  const float* value = (const float*)d_in[2];
  const float* pos   = (const float*)d_in[3];
  const float* Wq  = (const float*)d_in[4];
  const float* bq  = (const float*)d_in[5];
  const float* Wk  = (const float*)d_in[6];
  const float* bk  = (const float*)d_in[7];
  const float* Wv  = (const float*)d_in[8];
  const float* bv  = (const float*)d_in[9];
  const float* Wp  = (const float*)d_in[10];
  const float* Wo  = (const float*)d_in[11];
  const float* bo  = (const float*)d_in[12];
  const float* pbu = (const float*)d_in[13];
  const float* pbv = (const float*)d_in[14];

  float* out   = (float*)d_out;
  float* cache = out + 2097152;

  u16* ws     = (u16*)d_ws;
  u16* q_bf   = ws;
  u16* key_bf = ws + 2097152;
  u16* val_bf = ws + 5505024;
  u16* pos_bf = ws + 8912896;
  u16* Wq_bf  = ws + 9437184;
  u16* Wk_bf  = ws + 10485760;
  u16* Wv_bf  = ws + 11534336;
  u16* Wp_bf  = ws + 12582912;
  u16* Wo_bf  = ws + 13631488;
  u16* qatt   = ws + 14680064;
  u16* katt   = ws + 18874368;
  u16* vatt   = ws + 22282240;
  u16* patt   = ws + 25690112;
  u16* x_bf   = ws + 26148864;

  CvtArgs ca;
  ca.s[0] = { query,            q_bf,   2048 };
  ca.s[1] = { key,              key_bf, 3328 };
  ca.s[2] = { value,            val_bf, 3328 };
  ca.s[3] = { Wq,               Wq_bf,  1024 };
  ca.s[4] = { Wk,               Wk_bf,  1024 };
  ca.s[5] = { Wv,               Wv_bf,  1024 };
  ca.s[6] = { Wp,               Wp_bf,  1024 };
  ca.s[7] = { Wo,               Wo_bf,  1024 };
  ca.s[8] = { pos + 448*1024,   pos_bf, 448 };
  cvt_all<<<14272, 256, 0, stream>>>(ca);

  G4Args ga;
  ga.q = q_bf; ga.k = key_bf; ga.v = val_bf; ga.p = pos_bf;
  ga.Wq = Wq_bf; ga.Wk = Wk_bf; ga.Wv = Wv_bf; ga.Wp = Wp_bf;
  ga.bq = bq; ga.bk = bk; ga.bv = bv;
  ga.qatt = qatt; ga.katt = katt; ga.vatt = vatt; ga.patt = patt;
  ga.cache = cache;
  gemm4<<<576, 256, 0, stream>>>(ga);

  attn_v3<<<512, 256, 0, stream>>>(qatt, katt, vatt, patt, pbu, pbv, x_bf);

  gemm_out<<<512, 256, 0, stream>>>(x_bf, Wo_bf, bo, out);
}